// Round 13
// baseline (174.137 us; speedup 1.0000x reference)
//
#include <hip/hip_runtime.h>

// Navier-Stokes physics-informed loss (f32 in, scalar f32 out).
// x,y: (64,3,512,512). Interior: b in [1,62], i,j in [1,510].
// r0 = |dudx + dvdy| ; r1 = |dudt + u*dudx + v*dudy + dpdx - MU*lap u| ;
// r2 = |dvdt + u*dvdx + v*dvdy + dpdy - MU*lap v|
// dudt = (u[b+1]-u[b-1])*32 ; central *127.5 ; MU/DX^2 = 0.65025
//
// R4-R12: five structures pinned at wall 142+-2us. VALUBusy*dur ~= 43us
// constant (VALU fully explained); ~120us is stall. m69 cliff: waves/SIMD
// halves at VGPR 64->65. ALL plateau kernels sit at VGPR 76-92 = 4
// waves/SIMD; a no-spill VGPR<=64 full-grid config has never been run.
// R13: drop carried centers (-32 VGPR held forever), split each tensor's
// work into 3 small load->compute phases (U:8, V:6, P:4 loads) fenced by
// sched_barrier(0) so the compiler can't re-hoist into one fat batch.
// Target: honest VGPR<=64 -> 8 waves/SIMD. Grid 2040 = 255 i-pairs x 8
// b-chunks (z-major per XCD), single round at 8 blocks/CU.

constexpr int Wd   = 512;
constexpr int CSTR = 512 * 512;
constexpr int BSTR = 3 * 512 * 512;

__device__ __forceinline__ float4 ld4(const float* p) {
    return *reinterpret_cast<const float4*>(p);
}
__device__ __forceinline__ float4 ld4u(const float* p) {   // align-4 ok
    float4 v;
    __builtin_memcpy(&v, p, 16);
    return v;
}

// Phase-structured residuals for one tensor at one plane. No carried state.
__device__ __forceinline__ void tensor_resid(
    const float* __restrict__ T, int c,
    float s, float sdx, float slap, float sdt,
    float r0[4], float r1[4], float r2[4])
{
    // ---------- phase U: 8 loads ----------
    const float4 ubp = ld4 (T + c + BSTR);
    const float4 ubm = ld4 (T + c - BSTR);
    const float4 uc4 = ld4 (T + c);
    const float4 vc4 = ld4 (T + c + CSTR);
    const float4 uxp = ld4 (T + c + Wd);
    const float4 uxm = ld4 (T + c - Wd);
    const float4 uyp = ld4u(T + c + 1);
    const float4 uym = ld4u(T + c - 1);

    float dudx[4], ucs[4], vcs[4], r1p[4];
    {
        const float ubpA[4] = {ubp.x, ubp.y, ubp.z, ubp.w};
        const float ubmA[4] = {ubm.x, ubm.y, ubm.z, ubm.w};
        const float ucA[4]  = {uc4.x, uc4.y, uc4.z, uc4.w};
        const float vcA[4]  = {vc4.x, vc4.y, vc4.z, vc4.w};
        const float uxpA[4] = {uxp.x, uxp.y, uxp.z, uxp.w};
        const float uxmA[4] = {uxm.x, uxm.y, uxm.z, uxm.w};
        const float uypA[4] = {uyp.x, uyp.y, uyp.z, uyp.w};
        const float uymA[4] = {uym.x, uym.y, uym.z, uym.w};
        #pragma unroll
        for (int k = 0; k < 4; ++k) {
            ucs[k]  = ucA[k] * s;
            vcs[k]  = vcA[k] * s;
            dudx[k] = (uxpA[k] - uxmA[k]) * sdx;
            const float dudy = (uypA[k] - uymA[k]) * sdx;
            const float lapu = (uxpA[k] + uxmA[k] + uypA[k] + uymA[k]) * slap
                             - 2.601f * ucs[k];
            r1p[k] = (ubpA[k] - ubmA[k]) * sdt
                   + ucs[k] * dudx[k] + vcs[k] * dudy - lapu;
        }
    }
    __builtin_amdgcn_sched_barrier(0);

    // ---------- phase V: 6 loads ----------
    const float4 vbp = ld4 (T + c + CSTR + BSTR);
    const float4 vbm = ld4 (T + c + CSTR - BSTR);
    const float4 vxp = ld4 (T + c + CSTR + Wd);
    const float4 vxm = ld4 (T + c + CSTR - Wd);
    const float4 vyp = ld4u(T + c + CSTR + 1);
    const float4 vym = ld4u(T + c + CSTR - 1);

    float r2p[4];
    {
        const float vbpA[4] = {vbp.x, vbp.y, vbp.z, vbp.w};
        const float vbmA[4] = {vbm.x, vbm.y, vbm.z, vbm.w};
        const float vxpA[4] = {vxp.x, vxp.y, vxp.z, vxp.w};
        const float vxmA[4] = {vxm.x, vxm.y, vxm.z, vxm.w};
        const float vypA[4] = {vyp.x, vyp.y, vyp.z, vyp.w};
        const float vymA[4] = {vym.x, vym.y, vym.z, vym.w};
        #pragma unroll
        for (int k = 0; k < 4; ++k) {
            const float dvdx = (vxpA[k] - vxmA[k]) * sdx;
            const float dvdy = (vypA[k] - vymA[k]) * sdx;
            const float lapv = (vxpA[k] + vxmA[k] + vypA[k] + vymA[k]) * slap
                             - 2.601f * vcs[k];
            r0[k]  = fabsf(dudx[k] + dvdy);
            r2p[k] = (vbpA[k] - vbmA[k]) * sdt
                   + ucs[k] * dvdx + vcs[k] * dvdy - lapv;
        }
    }
    __builtin_amdgcn_sched_barrier(0);

    // ---------- phase P: 4 loads ----------
    const float4 pxp = ld4 (T + c + 2 * CSTR + Wd);
    const float4 pxm = ld4 (T + c + 2 * CSTR - Wd);
    const float4 pyp = ld4u(T + c + 2 * CSTR + 1);
    const float4 pym = ld4u(T + c + 2 * CSTR - 1);
    {
        const float pxpA[4] = {pxp.x, pxp.y, pxp.z, pxp.w};
        const float pxmA[4] = {pxm.x, pxm.y, pxm.z, pxm.w};
        const float pypA[4] = {pyp.x, pyp.y, pyp.z, pyp.w};
        const float pymA[4] = {pym.x, pym.y, pym.z, pym.w};
        #pragma unroll
        for (int k = 0; k < 4; ++k) {
            r1[k] = fabsf(r1p[k] + (pxpA[k] - pxmA[k]) * sdx);
            r2[k] = fabsf(r2p[k] + (pypA[k] - pymA[k]) * sdx);
        }
    }
    __builtin_amdgcn_sched_barrier(0);
}

__global__ __launch_bounds__(256)
void ns_loss_kernel(const float* __restrict__ X, const float* __restrict__ Y,
                    const float* __restrict__ stdp, double* __restrict__ acc)
{
    const float s    = *stdp;
    const float sdx  = s * 127.5f;
    const float slap = s * 0.65025f;
    const float sdt  = s * 32.0f;

    // XCD swizzle: nwg = 2040 = 8*255; z-major -> XCD k owns b-chunk k,
    // all 255 i-pairs consecutive within its L2.
    const int orig = blockIdx.x;
    const int z = orig & 7;              // b-chunk 0..7 (== XCD)
    const int y = orig >> 3;             // i-pair 0..254

    const int tid = threadIdx.x;
    const int jt  = tid & 127;
    const int io  = tid >> 7;
    const int i   = 1 + 2 * y + io;      // 1..510
    const int j0  = jt << 2;             // 0..508
    const int bs  = 1 + 8 * z;
    const int nsteps = min(8, 62 - 8 * z);   // 8,...,8,6

    int c = bs * BSTR + i * Wd + j0;

    const bool eL = (j0 == 0);
    const bool eR = (j0 == 508);

    float s0 = 0.0f, s1 = 0.0f, s2 = 0.0f;

    for (int it = 0; it < nsteps; ++it) {
        float r0x[4], r1x[4], r2x[4], r0y[4], r1y[4], r2y[4];
        tensor_resid(X, c, s, sdx, slap, sdt, r0x, r1x, r2x);
        tensor_resid(Y, c, s, sdx, slap, sdt, r0y, r1y, r2y);
        #pragma unroll
        for (int k = 0; k < 4; ++k) {
            float e0 = r0y[k] - r0x[k];
            float e1 = r1y[k] - r1x[k];
            float e2 = r2y[k] - r2x[k];
            if (k == 0) { e0 = eL ? 0.0f : e0; e1 = eL ? 0.0f : e1; e2 = eL ? 0.0f : e2; }
            if (k == 3) { e0 = eR ? 0.0f : e0; e1 = eR ? 0.0f : e1; e2 = eR ? 0.0f : e2; }
            s0 += e0 * e0;
            s1 += e1 * e1;
            s2 += e2 * e2;
        }
        c += BSTR;
    }

    // block reduction: f32 wave shuffle -> LDS -> f64 atomic per block
    for (int o = 32; o > 0; o >>= 1) {
        s0 += __shfl_down(s0, o);
        s1 += __shfl_down(s1, o);
        s2 += __shfl_down(s2, o);
    }
    __shared__ float sm[3][4];
    const int wid = threadIdx.x >> 6, lane = threadIdx.x & 63;
    if (lane == 0) { sm[0][wid] = s0; sm[1][wid] = s1; sm[2][wid] = s2; }
    __syncthreads();
    if (threadIdx.x == 0) {
        atomicAdd(&acc[0], (double)sm[0][0] + (double)sm[0][1]
                         + (double)sm[0][2] + (double)sm[0][3]);
        atomicAdd(&acc[1], (double)sm[1][0] + (double)sm[1][1]
                         + (double)sm[1][2] + (double)sm[1][3]);
        atomicAdd(&acc[2], (double)sm[2][0] + (double)sm[2][1]
                         + (double)sm[2][2] + (double)sm[2][3]);
    }
}

__global__ void ns_finalize_kernel(const double* __restrict__ acc,
                                   float* __restrict__ out)
{
    if (threadIdx.x == 0) {
        const double N = 62.0 * 510.0 * 510.0;
        out[0] = (float)(1.0e-3 * (acc[0] + acc[1] + acc[2]) / N);
    }
}

extern "C" void kernel_launch(void* const* d_in, const int* in_sizes, int n_in,
                              void* d_out, int out_size, void* d_ws, size_t ws_size,
                              hipStream_t stream) {
    const float* X    = (const float*)d_in[0];
    const float* Y    = (const float*)d_in[1];
    const float* stdp = (const float*)d_in[2];
    float* out  = (float*)d_out;
    double* acc = (double*)d_ws;

    hipMemsetAsync(acc, 0, 3 * sizeof(double), stream);

    dim3 block(256);
    dim3 grid(2040);   // 255 i-pairs x 8 b-chunks; single round at VGPR<=64
    ns_loss_kernel<<<grid, block, 0, stream>>>(X, Y, stdp, acc);
    ns_finalize_kernel<<<1, 64, 0, stream>>>(acc, out);
}

// Round 14
// 124.294 us; speedup vs baseline: 1.4010x; 1.4010x over previous
//
#include <hip/hip_runtime.h>

// Navier-Stokes physics-informed loss (f32 in, scalar f32 out).
// x,y: (64,3,512,512). Interior: b in [1,62], i,j in [1,510].
// r0 = |dudx + dvdy| ; r1 = |dudt + u*dudx + v*dudy + dpdx - MU*lap u| ;
// r2 = |dvdt + u*dvdx + v*dvdy + dpdy - MU*lap v| ; dudt=(u[b+1]-u[b-1])*32
//
// EMPIRICAL LAW (R2-R13): requested-bytes service pinned at ~10-11 TB/s
// (~18 B/cy/CU) independent of waves (8-32/CU), request width, VGPR,
// pipelining. Only lever: cut requested bytes (1.81 GB vs 0.40 unique).
// R9 cut to 0.66 GB via LDS but __syncthreads serialized fresh-load latency.
// R14 = R9 sharing + T14 prefetch-1-plane-ahead + raw s_barrier with
// lgkmcnt(0) only (global prefetches stay in flight across barriers):
//  - block = 512 thr = 4 rows x 128 float4-cols; marches b within a chunk
//  - LDS stages u,v (scaled) + p (raw) center rows FROM REGISTERS
//    (centers already carried for the b-march -> no reload)
//  - i+-1 rows from LDS (edge rows io=0/3 from prefetched regs)
//  - j+-1 via shfl (R2-proven), wave-boundary lanes from LDS scalar
//  - fresh global: nu,nv,cp (+edges for 2/8 waves) ~ 7.5 float4/iter/thread
//    vs 28 -> requested ~0.5 GB.

constexpr int Wd   = 512;
constexpr int CSTR = 512 * 512;
constexpr int BSTR = 3 * 512 * 512;

__device__ __forceinline__ float4 ld4(const float* p) {
    return *reinterpret_cast<const float4*>(p);
}
__device__ __forceinline__ float4 scale4(float4 a, float s) {
    return make_float4(a.x * s, a.y * s, a.z * s, a.w * s);
}

// Residuals for one tensor at the current plane.
// L: this tensor's LDS slab [field u,v,p][row 0..3][512 floats].
// eu,ev: SCALED edge row; ep RAW. mu,cu,nus: u at b-1,b,b+1 (all SCALED).
// cp: RAW own p center row.
__device__ __forceinline__ void plane_resid(
    const float (&L)[3][4][512],
    int io, int jt, int j0,
    float4 eu, float4 ev, float4 ep,
    float4 mu, float4 cu, float4 nus,
    float4 mv, float4 cv, float4 nvs,
    float4 cp, float sdx,
    float r0[4], float r1[4], float r2[4])
{
    float4 uxm, vxm, pxm, uxp, vxp, pxp;
    if (io == 0) { uxm = eu; vxm = ev; pxm = ep; }
    else {
        uxm = ld4(&L[0][io - 1][j0]);
        vxm = ld4(&L[1][io - 1][j0]);
        pxm = ld4(&L[2][io - 1][j0]);
    }
    if (io == 3) { uxp = eu; vxp = ev; pxp = ep; }
    else {
        uxp = ld4(&L[0][io + 1][j0]);
        vxp = ld4(&L[1][io + 1][j0]);
        pxp = ld4(&L[2][io + 1][j0]);
    }

    // j-neighbors: shfl on carried center regs; wave-boundary from LDS.
    float u_l = __shfl_up(cu.w, 1);
    float v_l = __shfl_up(cv.w, 1);
    float p_l = __shfl_up(cp.w, 1);
    float u_r = __shfl_down(cu.x, 1);
    float v_r = __shfl_down(cv.x, 1);
    float p_r = __shfl_down(cp.x, 1);
    const int lane = jt & 63;
    if (lane == 0) {                       // needs col j0-1 (garbage ok if j0==0: masked)
        const int jm = (j0 == 0) ? 0 : (j0 - 1);
        u_l = L[0][io][jm]; v_l = L[1][io][jm]; p_l = L[2][io][jm];
    }
    if (lane == 63) {                      // needs col j0+4 (clamped; masked at j0==508)
        const int jp = (j0 >= 508) ? 511 : (j0 + 4);
        u_r = L[0][io][jp]; v_r = L[1][io][jp]; p_r = L[2][io][jp];
    }

    const float ucA[4] = {cu.x, cu.y, cu.z, cu.w};
    const float vcA[4] = {cv.x, cv.y, cv.z, cv.w};
    const float umA[4] = {mu.x, mu.y, mu.z, mu.w};
    const float vmA[4] = {mv.x, mv.y, mv.z, mv.w};
    const float unA[4] = {nus.x, nus.y, nus.z, nus.w};
    const float vnA[4] = {nvs.x, nvs.y, nvs.z, nvs.w};
    const float ul[4]  = {u_l, cu.x, cu.y, cu.z};
    const float ur[4]  = {cu.y, cu.z, cu.w, u_r};
    const float vl[4]  = {v_l, cv.x, cv.y, cv.z};
    const float vr[4]  = {cv.y, cv.z, cv.w, v_r};
    const float pl[4]  = {p_l, cp.x, cp.y, cp.z};
    const float pr[4]  = {cp.y, cp.z, cp.w, p_r};
    const float uxpA[4] = {uxp.x, uxp.y, uxp.z, uxp.w};
    const float uxmA[4] = {uxm.x, uxm.y, uxm.z, uxm.w};
    const float vxpA[4] = {vxp.x, vxp.y, vxp.z, vxp.w};
    const float vxmA[4] = {vxm.x, vxm.y, vxm.z, vxm.w};
    const float pxpA[4] = {pxp.x, pxp.y, pxp.z, pxp.w};
    const float pxmA[4] = {pxm.x, pxm.y, pxm.z, pxm.w};

    #pragma unroll
    for (int k = 0; k < 4; ++k) {
        const float dudx = (uxpA[k] - uxmA[k]) * 127.5f;   // scaled inputs
        const float dvdx = (vxpA[k] - vxmA[k]) * 127.5f;
        const float dpdx = (pxpA[k] - pxmA[k]) * sdx;      // raw p
        const float dudy = (ur[k] - ul[k]) * 127.5f;
        const float dvdy = (vr[k] - vl[k]) * 127.5f;
        const float dpdy = (pr[k] - pl[k]) * sdx;
        const float lapu = (uxpA[k] + uxmA[k] + ur[k] + ul[k]) * 0.65025f
                         - 2.601f * ucA[k];
        const float lapv = (vxpA[k] + vxmA[k] + vr[k] + vl[k]) * 0.65025f
                         - 2.601f * vcA[k];
        r0[k] = fabsf(dudx + dvdy);
        r1[k] = fabsf((unA[k] - umA[k]) * 32.0f + ucA[k] * dudx + vcA[k] * dudy
                      + dpdx - lapu);
        r2[k] = fabsf((vnA[k] - vmA[k]) * 32.0f + ucA[k] * dvdx + vcA[k] * dvdy
                      + dpdy - lapv);
    }
}

__global__ __launch_bounds__(512)
void ns_loss_kernel(const float* __restrict__ X, const float* __restrict__ Y,
                    const float* __restrict__ stdp, double* __restrict__ acc)
{
    __shared__ float lds[2][3][4][512];     // 48 KiB: [tensor][u,v,p][row][col]
    __shared__ float smr[3][8];

    const float s   = *stdp;
    const float sdx = s * 127.5f;

    // XCD swizzle: nwg = 512 = 8*64; z-major, band-minor.
    const int orig = blockIdx.x;
    const int wg   = (orig & 7) * 64 + (orig >> 3);
    const int z    = wg >> 7;              // b-chunk 0..3 (15,15,16,16 planes)
    const int band = wg & 127;             // i-band 0..127

    const int tid = threadIdx.x;
    const int jt  = tid & 127;
    const int io  = tid >> 7;
    const int j0  = jt << 2;
    const int irow = 1 + band * 4 + io;
    const int i    = min(irow, 511);
    const bool vrow = (irow <= 510);
    const int bs = 1 + 15 * z + (z == 3 ? 1 : 0);   // 1,16,31,47
    const int nsteps = (z < 2) ? 15 : 16;

    int c = bs * BSTR + i * Wd + j0;
    const int cup  = (i < 511) ? Wd : 0;
    const int eoff = (io == 0) ? -Wd : cup;          // edge-row offset
    const bool isedge = (io == 0) || (io == 3);

    // ---- prologue: plane bs ----
    float4 xmu = scale4(ld4(X + c - BSTR), s);
    float4 xcu = scale4(ld4(X + c), s);
    float4 xmv = scale4(ld4(X + c - BSTR + CSTR), s);
    float4 xcv = scale4(ld4(X + c + CSTR), s);
    float4 ymu = scale4(ld4(Y + c - BSTR), s);
    float4 ycu = scale4(ld4(Y + c), s);
    float4 ymv = scale4(ld4(Y + c - BSTR + CSTR), s);
    float4 ycv = scale4(ld4(Y + c + CSTR), s);
    float4 xnu = ld4(X + c + BSTR);                 // raw u(b+1)
    float4 xnv = ld4(X + c + BSTR + CSTR);
    float4 xcp = ld4(X + c + 2 * CSTR);             // raw p center
    float4 ynu = ld4(Y + c + BSTR);
    float4 ynv = ld4(Y + c + BSTR + CSTR);
    float4 ycp = ld4(Y + c + 2 * CSTR);
    float4 xeu = make_float4(0,0,0,0), xev = xeu, xep = xeu;
    float4 yeu = xeu, yev = xeu, yep = xeu;
    if (isedge) {
        xeu = scale4(ld4(X + c + eoff), s);
        xev = scale4(ld4(X + c + CSTR + eoff), s);
        xep = ld4(X + c + 2 * CSTR + eoff);
        yeu = scale4(ld4(Y + c + eoff), s);
        yev = scale4(ld4(Y + c + CSTR + eoff), s);
        yep = ld4(Y + c + 2 * CSTR + eoff);
    }

    float s0 = 0.0f, s1 = 0.0f, s2 = 0.0f;

    for (int it = 0; it < nsteps; ++it) {
        const int cn = c + ((it + 1 < nsteps) ? BSTR : 0);

        // ---- 1. stage current plane from registers ----
        *(float4*)&lds[0][0][io][j0] = xcu;
        *(float4*)&lds[0][1][io][j0] = xcv;
        *(float4*)&lds[0][2][io][j0] = xcp;
        *(float4*)&lds[1][0][io][j0] = ycu;
        *(float4*)&lds[1][1][io][j0] = ycv;
        *(float4*)&lds[1][2][io][j0] = ycp;
        asm volatile("s_waitcnt lgkmcnt(0)" ::: "memory");
        __builtin_amdgcn_s_barrier();     // raw: prefetched globals stay in flight

        // ---- 2. snapshot b+1 centers (frees xnu/xnv), issue next prefetch ----
        const float4 xnus = scale4(xnu, s), xnvs = scale4(xnv, s);
        const float4 ynus = scale4(ynu, s), ynvs = scale4(ynv, s);
        xnu = ld4(X + cn + BSTR);                    // u(p+2)
        xnv = ld4(X + cn + BSTR + CSTR);
        ynu = ld4(Y + cn + BSTR);
        ynv = ld4(Y + cn + BSTR + CSTR);
        float4 xcp2 = ld4(X + cn + 2 * CSTR);        // p(p+1)
        float4 ycp2 = ld4(Y + cn + 2 * CSTR);
        float4 xeu2 = xeu, xev2 = xev, xep2 = xep;
        float4 yeu2 = yeu, yev2 = yev, yep2 = yep;
        if (isedge) {
            xeu2 = scale4(ld4(X + cn + eoff), s);
            xev2 = scale4(ld4(X + cn + CSTR + eoff), s);
            xep2 = ld4(X + cn + 2 * CSTR + eoff);
            yeu2 = scale4(ld4(Y + cn + eoff), s);
            yev2 = scale4(ld4(Y + cn + CSTR + eoff), s);
            yep2 = ld4(Y + cn + 2 * CSTR + eoff);
        }

        // ---- 3. compute from LDS + regs ----
        float r0x[4], r1x[4], r2x[4], r0y[4], r1y[4], r2y[4];
        plane_resid(lds[0], io, jt, j0, xeu, xev, xep,
                    xmu, xcu, xnus, xmv, xcv, xnvs, xcp, sdx, r0x, r1x, r2x);
        plane_resid(lds[1], io, jt, j0, yeu, yev, yep,
                    ymu, ycu, ynus, ymv, ycv, ynvs, ycp, sdx, r0y, r1y, r2y);

        // ---- 4. accumulate (masked) ----
        #pragma unroll
        for (int k = 0; k < 4; ++k) {
            float e0 = r0y[k] - r0x[k];
            float e1 = r1y[k] - r1x[k];
            float e2 = r2y[k] - r2x[k];
            const bool dead = (!vrow) || (k == 0 && j0 == 0)
                                      || (k == 3 && j0 == 508);
            if (dead) { e0 = 0.0f; e1 = 0.0f; e2 = 0.0f; }
            s0 += e0 * e0; s1 += e1 * e1; s2 += e2 * e2;
        }

        // ---- 5. rotate carries; fence reads before next overwrite ----
        xmu = xcu; xcu = xnus; xmv = xcv; xcv = xnvs;
        ymu = ycu; ycu = ynus; ymv = ycv; ycv = ynvs;
        xcp = xcp2; ycp = ycp2;
        xeu = xeu2; xev = xev2; xep = xep2;
        yeu = yeu2; yev = yev2; yep = yep2;
        asm volatile("s_waitcnt lgkmcnt(0)" ::: "memory");
        __builtin_amdgcn_s_barrier();
        c = cn;
    }

    // ---- reduction: f32 wave shuffle -> LDS -> f64 atomic ----
    for (int o = 32; o > 0; o >>= 1) {
        s0 += __shfl_down(s0, o);
        s1 += __shfl_down(s1, o);
        s2 += __shfl_down(s2, o);
    }
    const int wid = tid >> 6, lane = tid & 63;
    if (lane == 0) { smr[0][wid] = s0; smr[1][wid] = s1; smr[2][wid] = s2; }
    __syncthreads();
    if (tid == 0) {
        double t0 = 0, t1 = 0, t2 = 0;
        #pragma unroll
        for (int w = 0; w < 8; ++w) {
            t0 += (double)smr[0][w];
            t1 += (double)smr[1][w];
            t2 += (double)smr[2][w];
        }
        atomicAdd(&acc[0], t0);
        atomicAdd(&acc[1], t1);
        atomicAdd(&acc[2], t2);
    }
}

__global__ void ns_finalize_kernel(const double* __restrict__ acc,
                                   float* __restrict__ out)
{
    if (threadIdx.x == 0) {
        const double N = 62.0 * 510.0 * 510.0;
        out[0] = (float)(1.0e-3 * (acc[0] + acc[1] + acc[2]) / N);
    }
}

extern "C" void kernel_launch(void* const* d_in, const int* in_sizes, int n_in,
                              void* d_out, int out_size, void* d_ws, size_t ws_size,
                              hipStream_t stream) {
    const float* X    = (const float*)d_in[0];
    const float* Y    = (const float*)d_in[1];
    const float* stdp = (const float*)d_in[2];
    float* out  = (float*)d_out;
    double* acc = (double*)d_ws;

    hipMemsetAsync(acc, 0, 3 * sizeof(double), stream);

    dim3 block(512);
    dim3 grid(512);   // 128 i-bands x 4 b-chunks; 2 blk/CU -> single round
    ns_loss_kernel<<<grid, block, 0, stream>>>(X, Y, stdp, acc);
    ns_finalize_kernel<<<1, 64, 0, stream>>>(acc, out);
}